// Round 7
// baseline (1254.771 us; speedup 1.0000x reference)
//
#include <hip/hip_runtime.h>
#include <cmath>

#define NN   1000
#define TT   4
#define PP   10
#define DD   13
#define FF   128
#define HH   128
#define EAA  16
#define KDIM 64
#define EE   20000
#define I_NODE 91
#define I_EDGE 169
#define MROW  13000   // N*D

// Fill helper: each kernel zeroes a slice [zbase, zbase+zn) of M (float4 units)
__device__ __forceinline__ void fill_slice(float4* __restrict__ Mz, long zbase,
                                           long zn, int nthr) {
  long stride = (long)gridDim.x * nthr;
  float4 z = make_float4(0.f, 0.f, 0.f, 0.f);
  for (long i = zbase + (long)blockIdx.x * nthr + threadIdx.x; i < zbase + zn;
       i += stride)
    Mz[i] = z;
}

// ---------------- Kc: fused precompute of combined basis weights ------------
__global__ __launch_bounds__(192) void k_comb(
    const float* __restrict__ We, const float* __restrict__ cobE,
    const float* __restrict__ Wn, const float* __restrict__ cobN,
    float* __restrict__ Wcomb, float* __restrict__ Wnc) {
  int b = blockIdx.x, t = threadIdx.x;
  if (t >= I_EDGE) return;
  if (b < PP * KDIM) {
    int p = b >> 6;
    float acc = 0.f;
    const float* wrow = We + b * I_EDGE;
    const float* crow = cobE + p * I_EDGE * I_EDGE + t;
    for (int i = 0; i < I_EDGE; ++i) acc += wrow[i] * crow[i * I_EDGE];
    Wcomb[b * I_EDGE + t] = acc;
  } else {
    int tf = b - PP * KDIM;
    int ty = tf >> 7;
    float acc = 0.f;
    const float* wrow = Wn + tf * I_NODE;
    const float* crow = cobN + ty * I_NODE * I_EDGE + t;
    for (int i = 0; i < I_NODE; ++i) acc += wrow[i] * crow[i * I_EDGE];
    Wnc[tf * I_EDGE + t] = acc;
  }
}

// ---------------- K1: m = node_feats @ W_msg ; zero agg ; fill slice --------
__global__ __launch_bounds__(128) void k_node_msg(
    const float* __restrict__ nf, const float* __restrict__ Wmsg,
    float* __restrict__ m, float* __restrict__ agg,
    float4* __restrict__ Mz, long zbase, long zn) {
  fill_slice(Mz, zbase, zn, 128);
  int n = blockIdx.x, j = threadIdx.x;
  __shared__ float row[FF];
  row[j] = nf[n * FF + j];
  __syncthreads();
  float acc = 0.f;
#pragma unroll 8
  for (int f = 0; f < FF; ++f) acc += row[f] * Wmsg[f * FF + j];
  m[n * FF + j] = acc;
  agg[n * FF + j] = 0.f;
}

// ---------------- K2: symmetric segment sum via atomics ; fill slice --------
__global__ __launch_bounds__(256) void k_scatter(
    const float* __restrict__ m, const int* __restrict__ src,
    const int* __restrict__ dst, float* __restrict__ agg,
    float4* __restrict__ Mz, long zbase, long zn) {
  fill_slice(Mz, zbase, zn, 256);
  int idx = blockIdx.x * 256 + threadIdx.x;
  if (idx >= EE * FF) return;
  int e = idx >> 7, j = idx & 127;
  int s = src[e], d = dst[e];
  atomicAdd(&agg[d * FF + j], m[s * FF + j]);
  atomicAdd(&agg[s * FF + j], m[d * FF + j]);
}

// ---------------- K3: node_h ; fill slice ----------------
__global__ __launch_bounds__(128) void k_node_h(
    const float* __restrict__ nf, const float* __restrict__ agg,
    const float* __restrict__ na, const float* __restrict__ Wattr,
    float* __restrict__ nh, float4* __restrict__ Mz, long zbase, long zn) {
  fill_slice(Mz, zbase, zn, 128);
  int n = blockIdx.x, j = threadIdx.x;
  float a = 0.f;
#pragma unroll
  for (int t = 0; t < TT; ++t) a += na[n * TT + t] * Wattr[t * FF + j];
  nh[n * FF + j] = nf[n * FF + j] + agg[n * FF + j] * (1.0f / 20.0f) + a;
}

// ---------------- K4: edge_msg = tanh(e_in @ W_em) ; fill slice -------------
#define EPB 8
__global__ __launch_bounds__(128) void k_edge_msg(
    const float* __restrict__ nh, const float* __restrict__ ef,
    const float* __restrict__ ea, const int* __restrict__ src,
    const int* __restrict__ dst, const float* __restrict__ Wem,
    float* __restrict__ emsg, float4* __restrict__ Mz, long zbase, long zn) {
  fill_slice(Mz, zbase, zn, 128);
  int e0 = blockIdx.x * EPB;
  int j = threadIdx.x;
  __shared__ float xin[EPB][2 * FF + 2 * EAA];  // [8][288]
  for (int e = 0; e < EPB; ++e) {
    int ee = e0 + e;
    int s = src[ee], d = dst[ee];
    for (int i = j; i < 288; i += 128) {
      float v;
      if (i < 128)      v = nh[s * FF + i];
      else if (i < 256) v = nh[d * FF + (i - 128)];
      else if (i < 272) v = ef[ee * EAA + (i - 256)];
      else              v = ea[ee * EAA + (i - 272)];
      xin[e][i] = v;
    }
  }
  __syncthreads();
  float acc[EPB];
#pragma unroll
  for (int e = 0; e < EPB; ++e) acc[e] = 0.f;
  for (int c = 0; c < 288; c += 4) {
    float4 xv[EPB];
#pragma unroll
    for (int e = 0; e < EPB; ++e) xv[e] = *(const float4*)&xin[e][c];
#pragma unroll
    for (int sub = 0; sub < 4; ++sub) {
      float w = Wem[(c + sub) * HH + j];
#pragma unroll
      for (int e = 0; e < EPB; ++e) {
        float x = (sub == 0) ? xv[e].x : (sub == 1) ? xv[e].y : (sub == 2) ? xv[e].z : xv[e].w;
        acc[e] += x * w;
      }
    }
  }
#pragma unroll
  for (int e = 0; e < EPB; ++e) emsg[(e0 + e) * HH + j] = tanhf(acc[e]);
}

// ---------------- K5: node diagonal blocks (fused basis), plain stores ------
__global__ __launch_bounds__(192) void k_node_block(
    const float* __restrict__ nh, const int* __restrict__ ntype,
    const float* __restrict__ Wnc, float* __restrict__ M) {
  int n = blockIdx.x, t = threadIdx.x;
  int ty = ntype[n];
  __shared__ float row[FF];
  if (t < FF) row[t] = nh[n * FF + t];
  __syncthreads();
  if (t < I_EDGE) {
    float acc = 0.f;
    const float* W = Wnc + ty * FF * I_EDGE + t;
#pragma unroll 4
    for (int f = 0; f < FF; ++f) acc += row[f] * W[f * I_EDGE];
    int x = t / DD, y = t % DD;
    M[(size_t)(n * DD + x) * MROW + (n * DD + y)] = acc;  // sole writer; edge atomics later
  }
}

// ---------------- K6: edge blocks, fused (h @ Wcomb), 2 edges/block ---------
#define E2 2
__global__ __launch_bounds__(256) void k_edge_blk(
    const float* __restrict__ nh, const float* __restrict__ emsg,
    const int* __restrict__ src, const int* __restrict__ dst,
    const int* __restrict__ etype, const float* __restrict__ Wproj,
    const float* __restrict__ Wcomb, float* __restrict__ M) {
  int e0 = blockIdx.x * E2;
  int t = threadIdx.x;
  __shared__ float xin[E2][384];     // [msg | nh_s | nh_d]
  __shared__ float hp[4][256];       // partials: e0ij, e0ji, e1ij, e1ji
  __shared__ float hv[4][KDIM];
  __shared__ float tji[E2][I_EDGE];
  __shared__ int se[E2], de[E2], pe[E2];

  if (t < E2) {
    int e = e0 + t;
    se[t] = src[e]; de[t] = dst[e]; pe[t] = etype[e];
  }
  __syncthreads();
  for (int e = 0; e < E2; ++e) {
    int ee = e0 + e, s = se[e], d = de[e];
    if (t < 128) {
      xin[e][t] = emsg[ee * HH + t];
      xin[e][256 + t] = nh[d * FF + t];
    } else {
      xin[e][t] = nh[s * FF + (t - 128)];
    }
  }
  __syncthreads();

  // phase A: h = x @ W_proj (384x64). rows <128 (msg) are shared between dirs.
  {
    int k = t & 63, seg = t >> 6;
    float a0 = 0.f, a1 = 0.f, a2 = 0.f, a3 = 0.f;
    const float* Wp = Wproj + k;
    int i0 = seg * 96;
    for (int c = i0; c < i0 + 96; c += 4) {
      float4 x0 = *(const float4*)&xin[0][c];
      float4 x1 = *(const float4*)&xin[1][c];
      float4 x0s, x1s;
      if (c < 128) { x0s = x0; x1s = x1; }     // msg segment: same for ij/ji
      else {
        int cs = (c < 256) ? c + 128 : c - 128;
        x0s = *(const float4*)&xin[0][cs];
        x1s = *(const float4*)&xin[1][cs];
      }
      float w0 = Wp[(c + 0) * KDIM], w1 = Wp[(c + 1) * KDIM];
      float w2 = Wp[(c + 2) * KDIM], w3 = Wp[(c + 3) * KDIM];
      a0 += x0.x * w0 + x0.y * w1 + x0.z * w2 + x0.w * w3;
      a1 += x0s.x * w0 + x0s.y * w1 + x0s.z * w2 + x0s.w * w3;
      a2 += x1.x * w0 + x1.y * w1 + x1.z * w2 + x1.w * w3;
      a3 += x1s.x * w0 + x1s.y * w1 + x1s.z * w2 + x1s.w * w3;
    }
    hp[0][t] = a0; hp[1][t] = a1; hp[2][t] = a2; hp[3][t] = a3;
  }
  __syncthreads();
  if (t < KDIM) {
#pragma unroll
    for (int q = 0; q < 4; ++q)
      hv[q][t] = hp[q][t] + hp[q][t + 64] + hp[q][t + 128] + hp[q][t + 192];
  }
  __syncthreads();

  // phase B: blk = h @ Wcomb[p] (64x169)
  float b0 = 0.f, b1 = 0.f, b2 = 0.f, b3 = 0.f;
  if (t < I_EDGE) {
    const float* W0 = Wcomb + pe[0] * KDIM * I_EDGE + t;
    const float* W1 = Wcomb + pe[1] * KDIM * I_EDGE + t;
    for (int k = 0; k < KDIM; k += 4) {
      float4 h0 = *(const float4*)&hv[0][k];
      float4 h1 = *(const float4*)&hv[1][k];
      float4 h2 = *(const float4*)&hv[2][k];
      float4 h3 = *(const float4*)&hv[3][k];
      float u0 = W0[(k + 0) * I_EDGE], u1 = W0[(k + 1) * I_EDGE];
      float u2 = W0[(k + 2) * I_EDGE], u3 = W0[(k + 3) * I_EDGE];
      float v0 = W1[(k + 0) * I_EDGE], v1 = W1[(k + 1) * I_EDGE];
      float v2 = W1[(k + 2) * I_EDGE], v3 = W1[(k + 3) * I_EDGE];
      b0 += h0.x * u0 + h0.y * u1 + h0.z * u2 + h0.w * u3;
      b1 += h1.x * u0 + h1.y * u1 + h1.z * u2 + h1.w * u3;
      b2 += h2.x * v0 + h2.y * v1 + h2.z * v2 + h2.w * v3;
      b3 += h3.x * v0 + h3.y * v1 + h3.z * v2 + h3.w * v3;
    }
    tji[0][t] = b1; tji[1][t] = b3;
  }
  __syncthreads();

  if (t < I_EDGE) {
    int x = t / DD, y = t % DD;
    int tr = y * DD + x;
    {
      int s = se[0], d = de[0];
      float eb = 0.5f * (b0 + tji[0][tr]);
      atomicAdd(&M[(size_t)(s * DD + x) * MROW + (d * DD + y)], eb);
      atomicAdd(&M[(size_t)(d * DD + y) * MROW + (s * DD + x)], eb);
    }
    {
      int s = se[1], d = de[1];
      float eb = 0.5f * (b2 + tji[1][tr]);
      atomicAdd(&M[(size_t)(s * DD + x) * MROW + (d * DD + y)], eb);
      atomicAdd(&M[(size_t)(d * DD + y) * MROW + (s * DD + x)], eb);
    }
  }
}

extern "C" void kernel_launch(void* const* d_in, const int* in_sizes, int n_in,
                              void* d_out, int out_size, void* d_ws, size_t ws_size,
                              hipStream_t stream) {
  const float* node_feats = (const float*)d_in[0];
  const float* node_attrs = (const float*)d_in[1];
  const float* edge_feats = (const float*)d_in[2];
  const float* edge_attrs = (const float*)d_in[3];
  const int*   edge_index = (const int*)d_in[4];
  const int*   node_types = (const int*)d_in[5];
  const int*   edge_types = (const int*)d_in[6];
  const float* W_msg  = (const float*)d_in[7];
  const float* W_attr = (const float*)d_in[8];
  const float* W_em   = (const float*)d_in[9];
  const float* W_proj = (const float*)d_in[10];
  const float* W_node = (const float*)d_in[11];
  const float* W_edge = (const float*)d_in[12];
  const float* cob_node = (const float*)d_in[13];
  const float* cob_edge = (const float*)d_in[14];

  float* M  = (float*)d_out;
  float4* M4 = (float4*)d_out;
  float* ws = (float*)d_ws;
  float* m_buf = ws;                  // N*F = 128000
  float* agg   = ws + 128000;         // N*F
  float* nh    = ws + 256000;         // N*F
  float* emsg  = ws + 384000;         // E*H = 2,560,000
  float* Wcomb = ws + 2944000;        // P*K*I_EDGE = 108,160
  float* Wnc   = ws + 3052160;        // T*F*I_EDGE = 86,528  (total ~12.6 MB)

  const int* src = edge_index;        // edge_index[0]
  const int* dst = edge_index + EE;   // edge_index[1]

  // fill slices (float4 units), total = out_size/4 = 42,250,000
  long n4 = (long)out_size / 4;
  long z1 = 3000000;                  // node_msg
  long z2 = 18000000;                 // scatter
  long z3 = 3000000;                  // node_h
  long z4 = n4 - z1 - z2 - z3;        // edge_msg (18,250,000)

  k_comb      <<<PP * KDIM + TT * FF, 192, 0, stream>>>(W_edge, cob_edge, W_node, cob_node, Wcomb, Wnc);
  k_node_msg  <<<NN, 128, 0, stream>>>(node_feats, W_msg, m_buf, agg, M4, 0, z1);
  k_scatter   <<<(EE * FF) / 256, 256, 0, stream>>>(m_buf, src, dst, agg, M4, z1, z2);
  k_node_h    <<<NN, 128, 0, stream>>>(node_feats, agg, node_attrs, W_attr, nh, M4, z1 + z2, z3);
  k_edge_msg  <<<EE / EPB, 128, 0, stream>>>(nh, edge_feats, edge_attrs, src, dst, W_em, emsg, M4, z1 + z2 + z3, z4);
  k_node_block<<<NN, 192, 0, stream>>>(nh, node_types, Wnc, M);
  k_edge_blk  <<<EE / E2, 256, 0, stream>>>(nh, emsg, src, dst, edge_types,
                                            W_proj, Wcomb, M);
}

// Round 8
// 1011.521 us; speedup vs baseline: 1.2405x; 1.2405x over previous
//
#include <hip/hip_runtime.h>
#include <cmath>

#define NN   1000
#define TT   4
#define PP   10
#define DD   13
#define FF   128
#define HH   128
#define EAA  16
#define KDIM 64
#define EE   20000
#define I_NODE 91
#define I_EDGE 169
#define MROW  13000   // N*D
#define BCAP 2560     // per-type bucket capacity (mean 2000, sd ~42)
#define EOB  8        // edges per block in k_edge_out
#define CHUNK (BCAP / EOB)  // 320

// ---------------- K0: zero 676MB output, one float4 store/thread (R3 best) --
__global__ __launch_bounds__(256) void k_zero(float4* __restrict__ p, long n4) {
  long i = (long)blockIdx.x * 256 + threadIdx.x;
  if (i < n4) p[i] = make_float4(0.f, 0.f, 0.f, 0.f);
}

__global__ void k_setup(int* __restrict__ cnt) {
  if (threadIdx.x < PP) cnt[threadIdx.x] = 0;
}

// ---------------- Kc: precompute Wcat (edge, both orientations) + Wnc -------
// b < PP*KDIM: Wcat[p][k][t]    = 0.5 * sum_i We[p][k][i] * cobE[p][i][t]
//              Wcat[p][64+k][t] = 0.5 * sum_i We[p][k][i] * cobE[p][i][tr]
// else:        Wnc[ty][f][t]    = sum_i Wn[ty][f][i] * cobN[ty][i][t]
__global__ __launch_bounds__(192) void k_comb(
    const float* __restrict__ We, const float* __restrict__ cobE,
    const float* __restrict__ Wn, const float* __restrict__ cobN,
    float* __restrict__ Wcat, float* __restrict__ Wnc) {
  int b = blockIdx.x, t = threadIdx.x;
  if (t >= I_EDGE) return;
  int x = t / DD, y = t % DD;
  int tr = y * DD + x;
  if (b < PP * KDIM) {
    int p = b >> 6, k = b & 63;
    float a = 0.f, c = 0.f;
    const float* wrow = We + b * I_EDGE;
    const float* cbase = cobE + p * I_EDGE * I_EDGE;
    for (int i = 0; i < I_EDGE; ++i) {
      float w = wrow[i];
      a += w * cbase[i * I_EDGE + t];
      c += w * cbase[i * I_EDGE + tr];
    }
    Wcat[(size_t)(p * 128 + k) * I_EDGE + t] = 0.5f * a;
    Wcat[(size_t)(p * 128 + 64 + k) * I_EDGE + t] = 0.5f * c;
  } else {
    int tf = b - PP * KDIM;
    int ty = tf >> 7;
    float acc = 0.f;
    const float* wrow = Wn + tf * I_NODE;
    const float* crow = cobN + ty * I_NODE * I_EDGE + t;
    for (int i = 0; i < I_NODE; ++i) acc += wrow[i] * crow[i * I_EDGE];
    Wnc[tf * I_EDGE + t] = acc;
  }
}

// ---------------- K1: m = node_feats @ W_msg ; zero agg ----------------
__global__ __launch_bounds__(128) void k_node_msg(
    const float* __restrict__ nf, const float* __restrict__ Wmsg,
    float* __restrict__ m, float* __restrict__ agg) {
  int n = blockIdx.x, j = threadIdx.x;
  __shared__ float row[FF];
  row[j] = nf[n * FF + j];
  __syncthreads();
  float acc = 0.f;
#pragma unroll 8
  for (int f = 0; f < FF; ++f) acc += row[f] * Wmsg[f * FF + j];
  m[n * FF + j] = acc;
  agg[n * FF + j] = 0.f;
}

// ---------------- K2: symmetric segment sum via atomics ; bucket types ------
__global__ __launch_bounds__(256) void k_scatter(
    const float* __restrict__ m, const int* __restrict__ src,
    const int* __restrict__ dst, float* __restrict__ agg) {
  int idx = blockIdx.x * 256 + threadIdx.x;
  if (idx >= EE * FF) return;
  int e = idx >> 7, j = idx & 127;
  int s = src[e], d = dst[e];
  atomicAdd(&agg[d * FF + j], m[s * FF + j]);
  atomicAdd(&agg[s * FF + j], m[d * FF + j]);
}

__global__ __launch_bounds__(256) void k_bucket(
    const int* __restrict__ etype, int* __restrict__ cnt, int* __restrict__ list) {
  int e = blockIdx.x * 256 + threadIdx.x;
  if (e >= EE) return;
  int p = etype[e];
  int r = atomicAdd(&cnt[p], 1);
  if (r < BCAP) list[p * BCAP + r] = e;
}

// ---------------- K3: node_h ----------------
__global__ __launch_bounds__(128) void k_node_h(
    const float* __restrict__ nf, const float* __restrict__ agg,
    const float* __restrict__ na, const float* __restrict__ Wattr,
    float* __restrict__ nh) {
  int n = blockIdx.x, j = threadIdx.x;
  float a = 0.f;
#pragma unroll
  for (int t = 0; t < TT; ++t) a += na[n * TT + t] * Wattr[t * FF + j];
  nh[n * FF + j] = nf[n * FF + j] + agg[n * FF + j] * (1.0f / 20.0f) + a;
}

// ---------------- K4: edge_msg = tanh(e_in @ W_em), 8 edges/block -----------
#define EPB 8
__global__ __launch_bounds__(128) void k_edge_msg(
    const float* __restrict__ nh, const float* __restrict__ ef,
    const float* __restrict__ ea, const int* __restrict__ src,
    const int* __restrict__ dst, const float* __restrict__ Wem,
    float* __restrict__ emsg) {
  int e0 = blockIdx.x * EPB;
  int j = threadIdx.x;
  __shared__ float xin[EPB][2 * FF + 2 * EAA];  // [8][288]
  for (int e = 0; e < EPB; ++e) {
    int ee = e0 + e;
    int s = src[ee], d = dst[ee];
    for (int i = j; i < 288; i += 128) {
      float v;
      if (i < 128)      v = nh[s * FF + i];
      else if (i < 256) v = nh[d * FF + (i - 128)];
      else if (i < 272) v = ef[ee * EAA + (i - 256)];
      else              v = ea[ee * EAA + (i - 272)];
      xin[e][i] = v;
    }
  }
  __syncthreads();
  float acc[EPB];
#pragma unroll
  for (int e = 0; e < EPB; ++e) acc[e] = 0.f;
  for (int c = 0; c < 288; c += 4) {
    float4 xv[EPB];
#pragma unroll
    for (int e = 0; e < EPB; ++e) xv[e] = *(const float4*)&xin[e][c];
#pragma unroll
    for (int sub = 0; sub < 4; ++sub) {
      float w = Wem[(c + sub) * HH + j];
#pragma unroll
      for (int e = 0; e < EPB; ++e) {
        float x = (sub == 0) ? xv[e].x : (sub == 1) ? xv[e].y : (sub == 2) ? xv[e].z : xv[e].w;
        acc[e] += x * w;
      }
    }
  }
#pragma unroll
  for (int e = 0; e < EPB; ++e) emsg[(e0 + e) * HH + j] = tanhf(acc[e]);
}

// ---------------- K5: B1 = nh @ Wproj[128:256], B2 = nh @ Wproj[256:384] ----
__global__ __launch_bounds__(128) void k_nodeproj(
    const float* __restrict__ nh, const float* __restrict__ Wproj,
    float* __restrict__ B1, float* __restrict__ B2) {
  int n = blockIdx.x, t = threadIdx.x;
  __shared__ float row[FF];
  row[t] = nh[n * FF + t];
  __syncthreads();
  int half = t >> 6, k = t & 63;
  const float* W = Wproj + (FF + half * FF) * KDIM + k;
  float acc = 0.f;
#pragma unroll 4
  for (int i = 0; i < FF; ++i) acc += row[i] * W[i * KDIM];
  (half ? B2 : B1)[n * KDIM + k] = acc;
}

// ---------------- K6: Hcat[e] = [Hmsg+B1[s]+B2[d] | Hmsg+B1[d]+B2[s]] -------
__global__ __launch_bounds__(256) void k_hmsg(
    const float* __restrict__ emsg, const int* __restrict__ src,
    const int* __restrict__ dst, const float* __restrict__ Wproj,
    const float* __restrict__ B1, const float* __restrict__ B2,
    float* __restrict__ Hcat) {
  int blk = blockIdx.x, t = threadIdx.x;
  int e_loc = t >> 6, k = t & 63;
  __shared__ float xm[4][HH];
  __shared__ int sL[4], dL[4];
  if (t < 4) {
    int e = blk * 4 + t;
    sL[t] = src[e]; dL[t] = dst[e];
  }
  for (int i = t; i < 4 * HH; i += 256)
    xm[i >> 7][i & 127] = emsg[(blk * 4 + (i >> 7)) * HH + (i & 127)];
  __syncthreads();
  float acc = 0.f;
  const float* Wp = Wproj + k;
  for (int c = 0; c < HH; c += 4) {
    float4 xv = *(const float4*)&xm[e_loc][c];
    acc += xv.x * Wp[(c + 0) * KDIM] + xv.y * Wp[(c + 1) * KDIM]
         + xv.z * Wp[(c + 2) * KDIM] + xv.w * Wp[(c + 3) * KDIM];
  }
  int e = blk * 4 + e_loc, s = sL[e_loc], d = dL[e_loc];
  Hcat[(size_t)e * 128 + k]      = acc + B1[s * KDIM + k] + B2[d * KDIM + k];
  Hcat[(size_t)e * 128 + 64 + k] = acc + B1[d * KDIM + k] + B2[s * KDIM + k];
}

// ---------------- K7: node diagonal blocks (fused basis), plain stores ------
__global__ __launch_bounds__(192) void k_node_block(
    const float* __restrict__ nh, const int* __restrict__ ntype,
    const float* __restrict__ Wnc, float* __restrict__ M) {
  int n = blockIdx.x, t = threadIdx.x;
  int ty = ntype[n];
  __shared__ float row[FF];
  if (t < FF) row[t] = nh[n * FF + t];
  __syncthreads();
  if (t < I_EDGE) {
    float acc = 0.f;
    const float* W = Wnc + ty * FF * I_EDGE + t;
#pragma unroll 4
    for (int f = 0; f < FF; ++f) acc += row[f] * W[f * I_EDGE];
    int x = t / DD, y = t % DD;
    M[(size_t)(n * DD + x) * MROW + (n * DD + y)] = acc;  // edge atomics come later
  }
}

// ---------------- K8: eb = Hcat[e] @ Wcat[p]; atomic scatter into M ---------
__global__ __launch_bounds__(256) void k_edge_out(
    const float* __restrict__ Hcat, const int* __restrict__ src,
    const int* __restrict__ dst, const int* __restrict__ cnt,
    const int* __restrict__ list, const float* __restrict__ Wcat,
    float* __restrict__ M) {
  int p = blockIdx.x / CHUNK;
  int base = (blockIdx.x % CHUNK) * EOB;
  int ecnt = cnt[p]; if (ecnt > BCAP) ecnt = BCAP;
  if (base >= ecnt) return;
  int nval = ecnt - base; if (nval > EOB) nval = EOB;
  int t = threadIdx.x;

  __shared__ float4 hv4[EOB][32];     // Hcat rows (128 floats each)
  __shared__ int eL[EOB], sL[EOB], dL[EOB];
  if (t < EOB) {
    int slot = (t < nval) ? t : 0;
    int e = list[p * BCAP + base + slot];
    eL[t] = e; sL[t] = src[e]; dL[t] = dst[e];
  }
  __syncthreads();
  {
    int e_loc = t >> 5, q = t & 31;
    hv4[e_loc][q] = ((const float4*)(Hcat + (size_t)eL[e_loc] * 128))[q];
  }
  __syncthreads();

  if (t >= I_EDGE) return;
  float acc[EOB];
#pragma unroll
  for (int e = 0; e < EOB; ++e) acc[e] = 0.f;
  const float* W = Wcat + (size_t)p * 128 * I_EDGE + t;
  for (int k4 = 0; k4 < 32; ++k4) {
    float w0 = W[(k4 * 4 + 0) * I_EDGE];
    float w1 = W[(k4 * 4 + 1) * I_EDGE];
    float w2 = W[(k4 * 4 + 2) * I_EDGE];
    float w3 = W[(k4 * 4 + 3) * I_EDGE];
#pragma unroll
    for (int e = 0; e < EOB; ++e) {
      float4 h = hv4[e][k4];
      acc[e] += h.x * w0 + h.y * w1 + h.z * w2 + h.w * w3;
    }
  }
  int x = t / DD, y = t % DD;
  for (int i = 0; i < nval; ++i) {
    int s = sL[i], d = dL[i];
    atomicAdd(&M[(size_t)(s * DD + x) * MROW + (d * DD + y)], acc[i]);
    atomicAdd(&M[(size_t)(d * DD + y) * MROW + (s * DD + x)], acc[i]);
  }
}

extern "C" void kernel_launch(void* const* d_in, const int* in_sizes, int n_in,
                              void* d_out, int out_size, void* d_ws, size_t ws_size,
                              hipStream_t stream) {
  const float* node_feats = (const float*)d_in[0];
  const float* node_attrs = (const float*)d_in[1];
  const float* edge_feats = (const float*)d_in[2];
  const float* edge_attrs = (const float*)d_in[3];
  const int*   edge_index = (const int*)d_in[4];
  const int*   node_types = (const int*)d_in[5];
  const int*   edge_types = (const int*)d_in[6];
  const float* W_msg  = (const float*)d_in[7];
  const float* W_attr = (const float*)d_in[8];
  const float* W_em   = (const float*)d_in[9];
  const float* W_proj = (const float*)d_in[10];
  const float* W_node = (const float*)d_in[11];
  const float* W_edge = (const float*)d_in[12];
  const float* cob_node = (const float*)d_in[13];
  const float* cob_edge = (const float*)d_in[14];

  float* M  = (float*)d_out;
  float* ws = (float*)d_ws;
  float* m_buf = ws;                       // N*F          = 128,000
  float* agg   = ws + 128000;              // N*F          = 128,000
  float* nh    = ws + 256000;              // N*F          = 128,000
  float* emsg  = ws + 384000;              // E*H          = 2,560,000
  float* Hcat  = ws + 2944000;             // E*128        = 2,560,000
  float* B1    = ws + 5504000;             // N*64         = 64,000
  float* B2    = ws + 5568000;             // N*64         = 64,000
  float* Wcat  = ws + 5632000;             // P*128*169    = 216,320
  float* Wnc   = ws + 5848320;             // T*F*169      = 86,528
  int*   cnt   = (int*)(ws + 5934848);     // 16
  int*   list  = cnt + 16;                 // P*BCAP = 25,600  (total ~23.9 MB)

  const int* src = edge_index;
  const int* dst = edge_index + EE;

  long n4 = (long)out_size / 4;
  k_zero      <<<(int)((n4 + 255) / 256), 256, 0, stream>>>((float4*)M, n4);
  k_setup     <<<1, 64, 0, stream>>>(cnt);
  k_comb      <<<PP * KDIM + TT * FF, 192, 0, stream>>>(W_edge, cob_edge, W_node, cob_node, Wcat, Wnc);
  k_bucket    <<<(EE + 255) / 256, 256, 0, stream>>>(edge_types, cnt, list);
  k_node_msg  <<<NN, 128, 0, stream>>>(node_feats, W_msg, m_buf, agg);
  k_scatter   <<<(EE * FF) / 256, 256, 0, stream>>>(m_buf, src, dst, agg);
  k_node_h    <<<NN, 128, 0, stream>>>(node_feats, agg, node_attrs, W_attr, nh);
  k_edge_msg  <<<EE / EPB, 128, 0, stream>>>(nh, edge_feats, edge_attrs, src, dst, W_em, emsg);
  k_nodeproj  <<<NN, 128, 0, stream>>>(nh, W_proj, B1, B2);
  k_hmsg      <<<EE / 4, 256, 0, stream>>>(emsg, src, dst, W_proj, B1, B2, Hcat);
  k_node_block<<<NN, 192, 0, stream>>>(nh, node_types, Wnc, M);
  k_edge_out  <<<PP * CHUNK, 256, 0, stream>>>(Hcat, src, dst, cnt, list, Wcat, M);
}